// Round 4
// baseline (51993.652 us; speedup 1.0000x reference)
//
#include <hip/hip_runtime.h>
#include <stdint.h>

#define BATCH 256
#define SEQT  512
#define DIM   128
#define HID   256
#define G3    768   // 3*HID
#define LSTR  264   // u16 row stride: 132 dwords, 16B-aligned rows

typedef unsigned short u16;
typedef unsigned int   u32;
typedef u16 u16x8 __attribute__((ext_vector_type(8)));
typedef float f32x4 __attribute__((ext_vector_type(4)));

static __device__ __forceinline__ float bflo(u32 w) { return __builtin_bit_cast(float, w << 16); }
static __device__ __forceinline__ float bfhi(u32 w) { return __builtin_bit_cast(float, w & 0xFFFF0000u); }
static __device__ __forceinline__ u16 f2bf(float f) {
  u32 x = __builtin_bit_cast(u32, f);
  x += 0x7FFFu + ((x >> 16) & 1u);
  return (u16)(x >> 16);
}
static __device__ __forceinline__ float sigm(float v) {
  return 1.f / (1.f + __expf(-v));
}

// 8-element bf16(weights) x f32(acts) dot accumulate
static __device__ __forceinline__ void dot8(float& acc, u16x8 wv, float4 a, float4 b) {
  u32 w0 = (u32)wv[0] | ((u32)wv[1] << 16);
  u32 w1 = (u32)wv[2] | ((u32)wv[3] << 16);
  u32 w2 = (u32)wv[4] | ((u32)wv[5] << 16);
  u32 w3 = (u32)wv[6] | ((u32)wv[7] << 16);
  acc += bflo(w0) * a.x; acc += bfhi(w0) * a.y;
  acc += bflo(w1) * a.z; acc += bfhi(w1) * a.w;
  acc += bflo(w2) * b.x; acc += bfhi(w2) * b.y;
  acc += bflo(w3) * b.z; acc += bfhi(w3) * b.w;
}

// ---------------- weight fp32 -> bf16 conversion ----------------
__global__ void convertk(const float* __restrict__ src, u16* __restrict__ dst, int n) {
  int i = blockIdx.x * 256 + threadIdx.x;
  if (i < n) dst[i] = f2bf(src[i]);
}

// ---------------- phase B: memory GRU, 1024 threads per batch row ----------------
// roles: tid<256 -> r-gate row tid (full dot); tid<512 -> z-gate row; tid>=512 -> n-gate half-dots
__launch_bounds__(1024, 4)
__global__ void gru_mem(const float* __restrict__ x,
                        const u16* __restrict__ Wib, const u16* __restrict__ Whb,
                        const float* __restrict__ bmi, const float* __restrict__ bmh,
                        u16* __restrict__ mem) {
  const int b = blockIdx.x, tid = threadIdx.x;
  __shared__ __align__(16) float hs[HID];
  __shared__ __align__(16) float xs[DIM];
  __shared__ __align__(16) float rs[HID], zs[HID];

  const int isN = tid >= 512;
  const int role = tid >> 8;             // 0=r 1=z (when !isN)
  const int rzc = tid & 255;
  const int nc = (tid - 512) >> 1;
  const int hf = tid & 1;

  float biasRZ = 0.f, binv = 0.f, bhnv = 0.f;
  const u16x8 *wi, *wh;
  if (!isN) {
    int row = role * HID + rzc;
    biasRZ = bmi[row] + bmh[row];
    wi = (const u16x8*)(Wib + (size_t)row * DIM);
    wh = (const u16x8*)(Whb + (size_t)row * HID);
  } else {
    int row = 2 * HID + nc;
    binv = bmi[row]; bhnv = bmh[row];
    wi = (const u16x8*)(Wib + (size_t)row * DIM + hf * (DIM / 2));
    wh = (const u16x8*)(Whb + (size_t)row * HID + hf * (HID / 2));
  }
  float hprev = 0.f;
  if (tid < HID) hs[tid] = 0.f;
  __syncthreads();

  for (int t = 0; t < SEQT; ++t) {
    if (tid < 32)
      ((f32x4*)xs)[tid] =
          __builtin_nontemporal_load(((const f32x4*)(x + ((size_t)b * SEQT + t) * DIM)) + tid);
    __syncthreads();               // xs ready, hs stable
    float ax = 0.f, ah = 0.f;
    if (!isN) {
      const float4* x4 = (const float4*)xs;
      const float4* h4 = (const float4*)hs;
      #pragma unroll 8
      for (int j = 0; j < DIM / 8; ++j) dot8(ax, wi[j], x4[2*j], x4[2*j+1]);
      #pragma unroll 8
      for (int j = 0; j < HID / 8; ++j) dot8(ah, wh[j], h4[2*j], h4[2*j+1]);
      float g = sigm(ax + ah + biasRZ);
      (role ? zs : rs)[rzc] = g;
    } else {
      const float4* x4 = (const float4*)(xs + hf * (DIM / 2));
      const float4* h4 = (const float4*)(hs + hf * (HID / 2));
      #pragma unroll 8
      for (int j = 0; j < DIM / 16; ++j) dot8(ax, wi[j], x4[2*j], x4[2*j+1]);
      #pragma unroll 8
      for (int j = 0; j < HID / 16; ++j) dot8(ah, wh[j], h4[2*j], h4[2*j+1]);
      ax += __shfl_xor(ax, 1);     // full input-side n dot
      ah += __shfl_xor(ah, 1);     // full hidden-side n dot
    }
    __syncthreads();               // rs, zs ready; hs reads done
    if (isN && !hf) {
      float n = tanhf(ax + binv + rs[nc] * (ah + bhnv));
      float h = (1.f - zs[nc]) * n + zs[nc] * hprev;
      hprev = h;
      hs[nc] = h;
      mem[((size_t)b * SEQT + t) * HID + nc] = f2bf(h);
    }
    __syncthreads();               // hs ready for next step
  }
}

// ---------------- decoder cell dots: one parallel phase per cell ----------------
template <int IN>
static __device__ __forceinline__ float cell_dots(const float* __restrict__ in,
                                                  const u16* __restrict__ Wb, int tid,
                                                  float biasRZ,
                                                  float* __restrict__ rs, float* __restrict__ zs) {
  if (tid < 512) {
    const int role = tid >> 8, c = tid & 255;
    const u16x8* w = (const u16x8*)(Wb + (size_t)(role * HID + c) * IN);
    const float4* in4 = (const float4*)in;
    float a = 0.f;
    #pragma unroll 8
    for (int j = 0; j < IN / 8; ++j) dot8(a, w[j], in4[2*j], in4[2*j+1]);
    float g = sigm(a + biasRZ);
    (role ? zs : rs)[c] = g;
    return 0.f;
  } else {
    const int c = (tid - 512) >> 1, hf = tid & 1;
    const u16x8* w = (const u16x8*)(Wb + (size_t)(2 * HID + c) * IN + hf * (IN / 2));
    const float4* in4 = (const float4*)(in + hf * (IN / 2));
    float a = 0.f;
    #pragma unroll 8
    for (int j = 0; j < IN / 16; ++j) dot8(a, w[j], in4[2*j], in4[2*j+1]);
    return a + __shfl_xor(a, 1);
  }
}

// ---------------- phase C: decoder scan, 1024 threads per batch row ----------------
__launch_bounds__(1024, 4)
__global__ void decoder(const float* __restrict__ x, const u16* __restrict__ mem,
                        const u16* __restrict__ W0b, const u16* __restrict__ W1b,
                        const u16* __restrict__ W2b, const u16* __restrict__ W3b,
                        const u16* __restrict__ W4b,
                        const float* __restrict__ bi0, const float* __restrict__ bh0,
                        const float* __restrict__ bi1, const float* __restrict__ bh1,
                        const float* __restrict__ bi2, const float* __restrict__ bh2,
                        const float* __restrict__ bi3, const float* __restrict__ bh3,
                        const float* __restrict__ bi4, const float* __restrict__ bh4,
                        const float* __restrict__ Wo, const float* __restrict__ bo,
                        float* __restrict__ out) {
  const int b = blockIdx.x, tid = threadIdx.x;
  const int lane = tid & 63, wave = tid >> 6;
  __shared__ __align__(16) u16 Lb0[64 * LSTR], Lb1[64 * LSTR];   // double-buffered 64x256 tiles
  __shared__ __align__(16) float pp[512];
  __shared__ __align__(16) float pvp[8][256];
  __shared__ __align__(16) float kst[HID];
  __shared__ __align__(16) float dv[DIM + HID];
  __shared__ __align__(16) float hA[HID], hB[HID];
  __shared__ __align__(16) float rs[HID], zs[HID];
  __shared__ float red[16], red2[16];

  const int isN = tid >= 512;
  const int role = tid >> 8;
  const int rzc = tid & 255;
  const int nc = (tid - 512) >> 1;
  const int hf = tid & 1;
  const int pidx = tid >> 1;          // score position
  const int c0 = (tid & 127) * 2;     // PV column pair
  const int sg = tid >> 7;            // PV s-eighth

  // per-cell biases for this thread's role
  float B0=0,B1=0,B2=0,B3=0,B4=0, Bi0=0,Bh0=0,Bi1=0,Bh1=0,Bi2=0,Bh2=0,Bi3=0,Bh3=0,Bi4=0,Bh4=0;
  if (!isN) {
    int rw = role * HID + rzc;
    B0 = bi0[rw] + bh0[rw]; B1 = bi1[rw] + bh1[rw]; B2 = bi2[rw] + bh2[rw];
    B3 = bi3[rw] + bh3[rw]; B4 = bi4[rw] + bh4[rw];
  } else {
    int rw = 2 * HID + nc;
    Bi0 = bi0[rw]; Bh0 = bh0[rw]; Bi1 = bi1[rw]; Bh1 = bh1[rw];
    Bi2 = bi2[rw]; Bh2 = bh2[rw]; Bi3 = bi3[rw]; Bh3 = bh3[rw];
    Bi4 = bi4[rw]; Bh4 = bh4[rw];
  }
  float wo0 = 0.f, wo1 = 0.f, wo2 = 0.f, wo3 = 0.f;
  const float bo0 = bo[0];
  if (wave == 0) { wo0 = Wo[lane]; wo1 = Wo[64+lane]; wo2 = Wo[128+lane]; wo3 = Wo[192+lane]; }
  if (tid < HID) kst[tid] = 0.f;
  __syncthreads();

  const u16* memb = mem + (size_t)b * SEQT * HID;

  for (int t = 0; t < SEQT; ++t) {
    // prefetch x row and tiles 0,1
    f32x4 xv;
    if (tid < 32)
      xv = __builtin_nontemporal_load(((const f32x4*)(x + ((size_t)b * SEQT + t) * DIM)) + tid);
    u16x8 sl[2][2];
    sl[0][0] = ((const u16x8*)memb)[tid];
    sl[0][1] = ((const u16x8*)memb)[tid + 1024];
    sl[1][0] = ((const u16x8*)(memb + 64 * HID))[tid];
    sl[1][1] = ((const u16x8*)(memb + 64 * HID))[tid + 1024];

    // ---- scores: thread = (position pidx, half hf), 128-elem half dot ----
    float s = 0.f;
    {
      const u16x8* mr = (const u16x8*)(memb + (size_t)pidx * HID + hf * 128);
      const float4* k4 = (const float4*)(kst + hf * 128);
      #pragma unroll 8
      for (int j = 0; j < 16; ++j) dot8(s, mr[j], k4[2*j], k4[2*j+1]);
      s += __shfl_xor(s, 1);
    }
    float mloc = s;
    #pragma unroll
    for (int off = 32; off; off >>= 1) mloc = fmaxf(mloc, __shfl_xor(mloc, off));
    if (lane == 0) red[wave] = mloc;

    // stage tiles 0,1 while scores' reduction settles
    {
      int cA = tid, cB = tid + 1024;
      *(u16x8*)(Lb0 + (cA >> 5) * LSTR + (cA & 31) * 8) = sl[0][0];
      *(u16x8*)(Lb0 + (cB >> 5) * LSTR + (cB & 31) * 8) = sl[0][1];
      *(u16x8*)(Lb1 + (cA >> 5) * LSTR + (cA & 31) * 8) = sl[1][0];
      *(u16x8*)(Lb1 + (cB >> 5) * LSTR + (cB & 31) * 8) = sl[1][1];
    }
    if (tid < 32) ((f32x4*)dv)[tid] = xv;
    __syncthreads();               // A: red, tiles 0/1, x staged

    float m = red[0];
    #pragma unroll
    for (int i = 1; i < 16; ++i) m = fmaxf(m, red[i]);
    float p0 = __expf(s - m);
    if (!hf) pp[pidx] = p0;
    float ls = hf ? 0.f : p0;
    #pragma unroll
    for (int off = 32; off; off >>= 1) ls += __shfl_xor(ls, off);
    if (lane == 0) red2[wave] = ls;  // read after later syncs

    // ---- PV: 8 tiles, double-buffered, 1 sync per tile ----
    float ctx0 = 0.f, ctx1 = 0.f;
    #pragma unroll
    for (int j = 0; j < 8; ++j) {
      // write tile j+1 (loaded at phase j-1) into buf (j+1)&1
      if (j >= 1 && j <= 6) {
        u16* wb = ((j + 1) & 1) ? Lb1 : Lb0;
        int cA = tid, cB = tid + 1024;
        *(u16x8*)(wb + (cA >> 5) * LSTR + (cA & 31) * 8) = sl[(j - 1) & 1][0];
        *(u16x8*)(wb + (cB >> 5) * LSTR + (cB & 31) * 8) = sl[(j - 1) & 1][1];
      }
      // load tile j+2
      if (j < 6) {
        const u16x8* sn = (const u16x8*)(memb + (size_t)(j + 2) * 64 * HID);
        sl[j & 1][0] = sn[tid];
        sl[j & 1][1] = sn[tid + 1024];
      }
      // compute tile j from buf j&1: 8 rows (sg), col pair c0
      {
        const u16* Lr = ((j & 1) ? Lb1 : Lb0) + (sg * 8) * LSTR + c0;
        const float* ppt = pp + j * 64 + sg * 8;
        float4 pa = *(const float4*)ppt, pb = *(const float4*)(ppt + 4);
        u32 w0 = *(const u32*)(Lr + 0 * LSTR);
        u32 w1 = *(const u32*)(Lr + 1 * LSTR);
        u32 w2 = *(const u32*)(Lr + 2 * LSTR);
        u32 w3 = *(const u32*)(Lr + 3 * LSTR);
        u32 w4 = *(const u32*)(Lr + 4 * LSTR);
        u32 w5 = *(const u32*)(Lr + 5 * LSTR);
        u32 w6 = *(const u32*)(Lr + 6 * LSTR);
        u32 w7 = *(const u32*)(Lr + 7 * LSTR);
        ctx0 += pa.x * bflo(w0); ctx1 += pa.x * bfhi(w0);
        ctx0 += pa.y * bflo(w1); ctx1 += pa.y * bfhi(w1);
        ctx0 += pa.z * bflo(w2); ctx1 += pa.z * bfhi(w2);
        ctx0 += pa.w * bflo(w3); ctx1 += pa.w * bfhi(w3);
        ctx0 += pb.x * bflo(w4); ctx1 += pb.x * bfhi(w4);
        ctx0 += pb.y * bflo(w5); ctx1 += pb.y * bfhi(w5);
        ctx0 += pb.z * bflo(w6); ctx1 += pb.z * bfhi(w6);
        ctx0 += pb.w * bflo(w7); ctx1 += pb.w * bfhi(w7);
      }
      if (j == 7) { pvp[sg][c0] = ctx0; pvp[sg][c0 + 1] = ctx1; }
      __syncthreads();
    }
    // ---- dv build: ctx = sum over s-eighths, normalized ----
    if (tid < HID) {
      float lsum = red2[0];
      #pragma unroll
      for (int i = 1; i < 16; ++i) lsum += red2[i];
      float c = pvp[0][tid] + pvp[1][tid] + pvp[2][tid] + pvp[3][tid] +
                pvp[4][tid] + pvp[5][tid] + pvp[6][tid] + pvp[7][tid];
      dv[DIM + tid] = c / lsum;
    }
    __syncthreads();               // dv complete

    // ---- 5 feed-forward GRU cells (1 dot-phase + 1 fix-phase each) ----
    float a;
    a = cell_dots<DIM + HID>(dv, W0b, tid, B0, rs, zs);
    __syncthreads();
    if (isN && !hf) hA[nc] = (1.f - zs[nc]) * tanhf(a + Bi0 + rs[nc] * Bh0);
    __syncthreads();
    a = cell_dots<HID>(hA, W1b, tid, B1, rs, zs);
    __syncthreads();
    if (isN && !hf) hB[nc] = (1.f - zs[nc]) * tanhf(a + Bi1 + rs[nc] * Bh1);
    __syncthreads();
    a = cell_dots<HID>(hB, W2b, tid, B2, rs, zs);
    __syncthreads();
    if (isN && !hf) hA[nc] = (1.f - zs[nc]) * tanhf(a + Bi2 + rs[nc] * Bh2);
    __syncthreads();
    a = cell_dots<HID>(hA, W3b, tid, B3, rs, zs);
    __syncthreads();
    if (isN && !hf) hB[nc] = (1.f - zs[nc]) * tanhf(a + Bi3 + rs[nc] * Bh3);
    __syncthreads();
    a = cell_dots<HID>(hB, W4b, tid, B4, rs, zs);
    __syncthreads();
    if (isN && !hf) kst[nc] = (1.f - zs[nc]) * tanhf(a + Bi4 + rs[nc] * Bh4);
    __syncthreads();               // kst stable for out + next step

    // ---- output layer (wave 0) ----
    if (wave == 0) {
      float acc = kst[lane] * wo0 + kst[64 + lane] * wo1 +
                  kst[128 + lane] * wo2 + kst[192 + lane] * wo3;
      #pragma unroll
      for (int off = 32; off; off >>= 1) acc += __shfl_xor(acc, off);
      if (lane == 0) out[(size_t)b * SEQT + t] = sigm(acc + bo0);
    }
  }
}

// ---------------- host ----------------
extern "C" void kernel_launch(void* const* d_in, const int* in_sizes, int n_in,
                              void* d_out, int out_size, void* d_ws, size_t ws_size,
                              hipStream_t stream) {
  const float* x    = (const float*)d_in[0];
  const float* Wmi  = (const float*)d_in[1];
  const float* Wmh  = (const float*)d_in[2];
  const float* bmi  = (const float*)d_in[3];
  const float* bmh  = (const float*)d_in[4];
  const float* Wd0  = (const float*)d_in[5];
  const float* bi0  = (const float*)d_in[6];
  const float* bh0  = (const float*)d_in[7];
  const float* Wd1  = (const float*)d_in[8];
  const float* bi1  = (const float*)d_in[9];
  const float* bh1  = (const float*)d_in[10];
  const float* Wd2  = (const float*)d_in[11];
  const float* bi2  = (const float*)d_in[12];
  const float* bh2  = (const float*)d_in[13];
  const float* Wk0  = (const float*)d_in[14];
  const float* bik0 = (const float*)d_in[15];
  const float* bhk0 = (const float*)d_in[16];
  const float* Wk1  = (const float*)d_in[17];
  const float* bik1 = (const float*)d_in[18];
  const float* bhk1 = (const float*)d_in[19];
  const float* Wo   = (const float*)d_in[20];
  const float* bo   = (const float*)d_in[21];

  u16* mem = (u16*)d_ws;
  size_t off = (size_t)BATCH * SEQT * HID;     // u16 units
  u16* Wmib = mem + off; off += (size_t)G3 * DIM;
  u16* Wmhb = mem + off; off += (size_t)G3 * HID;
  u16* W0b  = mem + off; off += (size_t)G3 * (DIM + HID);
  u16* W1b  = mem + off; off += (size_t)G3 * HID;
  u16* W2b  = mem + off; off += (size_t)G3 * HID;
  u16* W3b  = mem + off; off += (size_t)G3 * HID;
  u16* W4b  = mem + off; off += (size_t)G3 * HID;
  (void)ws_size; (void)in_sizes; (void)n_in; (void)out_size;

  convertk<<<(G3*DIM + 255) / 256, 256, 0, stream>>>(Wmi, Wmib, G3*DIM);
  convertk<<<(G3*HID + 255) / 256, 256, 0, stream>>>(Wmh, Wmhb, G3*HID);
  convertk<<<(G3*(DIM+HID) + 255) / 256, 256, 0, stream>>>(Wd0, W0b, G3*(DIM+HID));
  convertk<<<(G3*HID + 255) / 256, 256, 0, stream>>>(Wd1, W1b, G3*HID);
  convertk<<<(G3*HID + 255) / 256, 256, 0, stream>>>(Wd2, W2b, G3*HID);
  convertk<<<(G3*HID + 255) / 256, 256, 0, stream>>>(Wk0, W3b, G3*HID);
  convertk<<<(G3*HID + 255) / 256, 256, 0, stream>>>(Wk1, W4b, G3*HID);

  gru_mem<<<BATCH, 1024, 0, stream>>>(x, Wmib, Wmhb, bmi, bmh, mem);
  decoder<<<BATCH, 1024, 0, stream>>>(x, mem, W0b, W1b, W2b, W3b, W4b,
                                      bi0, bh0, bi1, bh1, bi2, bh2,
                                      bik0, bhk0, bik1, bhk1, Wo, bo,
                                      (float*)d_out);
}